// Round 1
// baseline (758.257 us; speedup 1.0000x reference)
//
#include <hip/hip_runtime.h>
#include <hip/hip_bf16.h>
#include <stdint.h>

// Problem: B=1, S=4096, HIDDEN=2048, HEADS=16, HEAD_DIM=128, causal MHA.
// All inputs fp32; output fp32. Compute in bf16 MFMA with fp32 accum.
//
// Workspace layout (bytes), total ~112 MB (assumes ws_size >= 118 MB):
//   xb   [4096][2048] bf16 @ 0          (16 MB)
//   WqT  [2048][2048] bf16 @ 16 MB      (8 MB)   (transposed: [out][in])
//   WkT  @ 24 MB, WvT @ 32 MB, WoT @ 40 MB
//   Qb   [4096][2048] bf16 @ 48 MB
//   Kb   [4096][2048] bf16 @ 64 MB
//   VTb  [2048][4096] bf16 @ 80 MB      (V transposed per-head: row h*128+d, col s)
//   Ctx  [4096][2048] bf16 @ 96 MB

#define SQ 4096
#define HID 2048
#define NH 16
#define HD 128

typedef __attribute__((ext_vector_type(8))) short bf16x8;
typedef __attribute__((ext_vector_type(4))) float f32x4;
typedef __attribute__((ext_vector_type(4))) unsigned short us4;

__device__ inline unsigned short f2bf(float f) {
    unsigned int u = __builtin_bit_cast(unsigned int, f);
    u = (u + 0x7FFFu + ((u >> 16) & 1u)) >> 16;
    return (unsigned short)u;
}

__device__ inline void gl2lds16(const void* g, void* l) {
    __builtin_amdgcn_global_load_lds(
        (const __attribute__((address_space(1))) unsigned int*)g,
        (__attribute__((address_space(3))) unsigned int*)l, 16, 0, 0);
}

// ---------------- fp32 -> bf16 convert (grid-stride, float4) ----------------
__global__ void cvt_f32_bf16(const float* __restrict__ src,
                             unsigned short* __restrict__ dst, int n) {
    int i = (blockIdx.x * blockDim.x + threadIdx.x) * 4;
    int stride = gridDim.x * blockDim.x * 4;
    for (; i < n; i += stride) {
        float4 v = *(const float4*)(src + i);
        us4 o;
        o.x = f2bf(v.x); o.y = f2bf(v.y); o.z = f2bf(v.z); o.w = f2bf(v.w);
        *(us4*)(dst + i) = o;
    }
}

// -------- transpose + convert: W [K][N] f32 -> WT [N][K] bf16 (2048x2048) ---
__global__ void transcvt(const float* __restrict__ W, unsigned short* __restrict__ WT) {
    __shared__ float tile[64][65];
    int n0 = blockIdx.x * 64, k0 = blockIdx.y * 64;
    int t = threadIdx.x;
    for (int i = 0; i < 4; i++) {
        int idx = i * 256 + t;          // 0..1023
        int k = idx >> 4;               // 64 rows, 16 float4 per row
        int n4 = (idx & 15) << 2;
        float4 v = *(const float4*)(W + (size_t)(k0 + k) * HID + n0 + n4);
        tile[k][n4 + 0] = v.x; tile[k][n4 + 1] = v.y;
        tile[k][n4 + 2] = v.z; tile[k][n4 + 3] = v.w;
    }
    __syncthreads();
    for (int i = 0; i < 4; i++) {
        int idx = i * 256 + t;
        int n = idx >> 4;
        int k4 = (idx & 15) << 2;
        us4 o;
        o.x = f2bf(tile[k4 + 0][n]); o.y = f2bf(tile[k4 + 1][n]);
        o.z = f2bf(tile[k4 + 2][n]); o.w = f2bf(tile[k4 + 3][n]);
        *(us4*)(WT + (size_t)(n0 + n) * HID + k0 + k4) = o;
    }
}

// ---------------- bf16 GEMM: C[M,N] = A[M,K] @ BT[N,K]^T (+bias) ------------
// M=4096, N=2048, K=2048. 128x128 tile, BK=64, 256 thr = 4 waves (2x2 of 64x64).
// OUTMODE 0: bf16 out [M][N] + bias; 1: bf16 out transposed [N][M] + bias;
//         2: f32 out [M][N], no bias.
template <int OUTMODE>
__global__ __launch_bounds__(256) void gemm_bf16(
    const unsigned short* __restrict__ A, const unsigned short* __restrict__ BT,
    const float* __restrict__ bias, void* __restrict__ C) {
    const int M = 4096, N = 2048, K = 2048;
    __shared__ __align__(16) unsigned short As[128 * 64];
    __shared__ __align__(16) unsigned short Bs[128 * 64];
    int m0 = blockIdx.x * 128, n0 = blockIdx.y * 128;
    int t = threadIdx.x;
    int lane = t & 63, wid = t >> 6;
    int wm = wid >> 1, wn = wid & 1;
    f32x4 acc[4][4] = {};

    for (int k0 = 0; k0 < K; k0 += 64) {
        for (int i = 0; i < 4; i++) {
            int idx = i * 256 + t;           // 1024 x 16B loads per tile
            int r = idx >> 3;                // row 0..127 (8 loads of 8 elems per row)
            int c = (idx & 7) << 3;
            void* ldsA = (void*)(As + ((i * 256 + wid * 64) << 3));
            void* ldsB = (void*)(Bs + ((i * 256 + wid * 64) << 3));
            gl2lds16(A + (size_t)(m0 + r) * K + k0 + c, ldsA);
            gl2lds16(BT + (size_t)(n0 + r) * K + k0 + c, ldsB);
        }
        __syncthreads();
        for (int kk = 0; kk < 2; kk++) {
            int ko = kk * 32 + ((lane >> 4) << 3);
            bf16x8 af[4], bfg[4];
            for (int mf = 0; mf < 4; mf++)
                af[mf] = *(const bf16x8*)(As + (wm * 64 + mf * 16 + (lane & 15)) * 64 + ko);
            for (int nf = 0; nf < 4; nf++)
                bfg[nf] = *(const bf16x8*)(Bs + (wn * 64 + nf * 16 + (lane & 15)) * 64 + ko);
            for (int mf = 0; mf < 4; mf++)
                for (int nf = 0; nf < 4; nf++)
                    acc[mf][nf] = __builtin_amdgcn_mfma_f32_16x16x32_bf16(
                        af[mf], bfg[nf], acc[mf][nf], 0, 0, 0);
        }
        __syncthreads();
    }

    int rbase = (lane >> 4) << 2;
    for (int mf = 0; mf < 4; mf++) {
        for (int nf = 0; nf < 4; nf++) {
            int n_g = n0 + wn * 64 + nf * 16 + (lane & 15);
            int m_base = m0 + wm * 64 + mf * 16 + rbase;
            float b = (OUTMODE == 2) ? 0.f : bias[n_g];
            if (OUTMODE == 0) {
                unsigned short* Cb = (unsigned short*)C;
                for (int r = 0; r < 4; r++)
                    Cb[(size_t)(m_base + r) * N + n_g] = f2bf(acc[mf][nf][r] + b);
            } else if (OUTMODE == 1) {
                unsigned short* Cb = (unsigned short*)C;
                us4 o;
                o.x = f2bf(acc[mf][nf][0] + b); o.y = f2bf(acc[mf][nf][1] + b);
                o.z = f2bf(acc[mf][nf][2] + b); o.w = f2bf(acc[mf][nf][3] + b);
                *(us4*)(Cb + (size_t)n_g * M + m_base) = o;
            } else {
                float* Cf = (float*)C;
                for (int r = 0; r < 4; r++)
                    Cf[(size_t)(m_base + r) * N + n_g] = acc[mf][nf][r];
            }
        }
    }
}

// ---------------- causal flash attention ------------------------------------
// grid (S/64, NH); 256 thr = 4 waves; wave w owns q rows q0+w*16..+15.
// K tiles of 64 staged in LDS [64][128]; V^T tiles in LDS [128][64].
__global__ __launch_bounds__(256) void attn(
    const unsigned short* __restrict__ Q, const unsigned short* __restrict__ Kc,
    const unsigned short* __restrict__ VT, unsigned short* __restrict__ O) {
    __shared__ __align__(16) unsigned short Kt[64 * 128];
    __shared__ __align__(16) unsigned short Vt[128 * 64];
    __shared__ __align__(16) unsigned short Pt[4][16 * 64];
    int q0 = blockIdx.x * 64;
    int h = blockIdx.y;
    int t = threadIdx.x, lane = t & 63, w = t >> 6;
    const float scale = 0.08838834764831845f;  // 1/sqrt(128)

    bf16x8 qf[4];
    {
        int qrow = q0 + w * 16 + (lane & 15);
        for (int ks = 0; ks < 4; ks++)
            qf[ks] = *(const bf16x8*)(Q + (size_t)qrow * HID + h * HD + ks * 32 + ((lane >> 4) << 3));
    }
    f32x4 o_acc[8] = {};
    float m_r[4], l_r[4];
    for (int r = 0; r < 4; r++) { m_r[r] = -1e30f; l_r[r] = 0.f; }

    int nt = q0 / 64 + 1;
    for (int tile = 0; tile < nt; tile++) {
        int kv0 = tile * 64;
        for (int i = 0; i < 4; i++) {
            int idx = i * 256 + t;
            int r = idx >> 4;                 // K: 64 rows, 16 loads/row
            int c = (idx & 15) << 3;
            gl2lds16(Kc + (size_t)(kv0 + r) * HID + h * HD + c,
                     (void*)(Kt + ((i * 256 + w * 64) << 3)));
            int r2 = idx >> 3;                // VT: 128 rows, 8 loads/row
            int c2 = (idx & 7) << 3;
            gl2lds16(VT + (size_t)(h * HD + r2) * SQ + kv0 + c2,
                     (void*)(Vt + ((i * 256 + w * 64) << 3)));
        }
        __syncthreads();

        // S = Q K^T  (per wave: 16 q-rows x 64 kv-cols)
        f32x4 sfr[4];
        for (int c = 0; c < 4; c++) {
            f32x4 s = {0.f, 0.f, 0.f, 0.f};
            for (int ks = 0; ks < 4; ks++) {
                bf16x8 kf = *(const bf16x8*)(Kt + (c * 16 + (lane & 15)) * 128 + ks * 32 + ((lane >> 4) << 3));
                s = __builtin_amdgcn_mfma_f32_16x16x32_bf16(qf[ks], kf, s, 0, 0, 0);
            }
            sfr[c] = s;
        }
        // scale + causal mask
        int rq = q0 + w * 16 + ((lane >> 4) << 2);
        for (int c = 0; c < 4; c++) {
            int kcol = kv0 + c * 16 + (lane & 15);
            for (int r = 0; r < 4; r++) {
                float v = sfr[c][r] * scale;
                sfr[c][r] = (kcol <= rq + r) ? v : -1e30f;
            }
        }
        // online softmax: row max across 4 frags + 16-lane group
        float alpha[4];
        for (int r = 0; r < 4; r++) {
            float v = fmaxf(fmaxf(sfr[0][r], sfr[1][r]), fmaxf(sfr[2][r], sfr[3][r]));
            v = fmaxf(v, __shfl_xor(v, 1));
            v = fmaxf(v, __shfl_xor(v, 2));
            v = fmaxf(v, __shfl_xor(v, 4));
            v = fmaxf(v, __shfl_xor(v, 8));
            float mn = fmaxf(m_r[r], v);
            alpha[r] = __expf(m_r[r] - mn);
            m_r[r] = mn;
        }
        float rs[4] = {0.f, 0.f, 0.f, 0.f};
        for (int c = 0; c < 4; c++)
            for (int r = 0; r < 4; r++) {
                float p = __expf(sfr[c][r] - m_r[r]);
                sfr[c][r] = p;
                rs[r] += p;
            }
        for (int r = 0; r < 4; r++) {
            float v = rs[r];
            v += __shfl_xor(v, 1); v += __shfl_xor(v, 2);
            v += __shfl_xor(v, 4); v += __shfl_xor(v, 8);
            l_r[r] = l_r[r] * alpha[r] + v;
        }
        for (int c2 = 0; c2 < 8; c2++)
            for (int r = 0; r < 4; r++) o_acc[c2][r] *= alpha[r];

        // P -> per-wave LDS buffer (re-fragment for PV A-operand)
        unsigned short* pw = &Pt[w][0];
        for (int c = 0; c < 4; c++)
            for (int r = 0; r < 4; r++)
                pw[(((lane >> 4) << 2) + r) * 64 + c * 16 + (lane & 15)] = f2bf(sfr[c][r]);
        asm volatile("s_waitcnt lgkmcnt(0)" ::: "memory");

        // O += P V   (A = P [16 x 64], B = V [64 x 128] via VT LDS)
        for (int kk = 0; kk < 2; kk++) {
            bf16x8 pa = *(const bf16x8*)(pw + (lane & 15) * 64 + kk * 32 + ((lane >> 4) << 3));
            for (int c2 = 0; c2 < 8; c2++) {
                bf16x8 bv = *(const bf16x8*)(Vt + (c2 * 16 + (lane & 15)) * 64 + kk * 32 + ((lane >> 4) << 3));
                o_acc[c2] = __builtin_amdgcn_mfma_f32_16x16x32_bf16(pa, bv, o_acc[c2], 0, 0, 0);
            }
        }
        __syncthreads();
    }

    for (int c2 = 0; c2 < 8; c2++)
        for (int r = 0; r < 4; r++) {
            int row = q0 + w * 16 + ((lane >> 4) << 2) + r;
            O[(size_t)row * HID + h * HD + c2 * 16 + (lane & 15)] = f2bf(o_acc[c2][r] / l_r[r]);
        }
}

// ---------------------------------------------------------------------------
extern "C" void kernel_launch(void* const* d_in, const int* in_sizes, int n_in,
                              void* d_out, int out_size, void* d_ws, size_t ws_size,
                              hipStream_t stream) {
    const float* x  = (const float*)d_in[0];
    const float* Wq = (const float*)d_in[1];
    const float* bq = (const float*)d_in[2];
    const float* Wk = (const float*)d_in[3];
    const float* bk = (const float*)d_in[4];
    const float* Wv = (const float*)d_in[5];
    const float* bv = (const float*)d_in[6];
    const float* Wo = (const float*)d_in[7];

    char* ws = (char*)d_ws;
    const size_t MB = 1024 * 1024;
    unsigned short* xb  = (unsigned short*)(ws + 0 * MB);
    unsigned short* WqT = (unsigned short*)(ws + 16 * MB);
    unsigned short* WkT = (unsigned short*)(ws + 24 * MB);
    unsigned short* WvT = (unsigned short*)(ws + 32 * MB);
    unsigned short* WoT = (unsigned short*)(ws + 40 * MB);
    unsigned short* Qb  = (unsigned short*)(ws + 48 * MB);
    unsigned short* Kb  = (unsigned short*)(ws + 64 * MB);
    unsigned short* VTb = (unsigned short*)(ws + 80 * MB);
    unsigned short* Ctx = (unsigned short*)(ws + 96 * MB);

    // 1. x -> bf16
    cvt_f32_bf16<<<8192, 256, 0, stream>>>(x, xb, SQ * HID);
    // 2. weights -> transposed bf16
    dim3 tg(HID / 64, HID / 64);
    transcvt<<<tg, 256, 0, stream>>>(Wq, WqT);
    transcvt<<<tg, 256, 0, stream>>>(Wk, WkT);
    transcvt<<<tg, 256, 0, stream>>>(Wv, WvT);
    transcvt<<<tg, 256, 0, stream>>>(Wo, WoT);
    // 3. QKV projections
    dim3 gg(SQ / 128, HID / 128);
    gemm_bf16<0><<<gg, 256, 0, stream>>>(xb, WqT, bq, (void*)Qb);
    gemm_bf16<0><<<gg, 256, 0, stream>>>(xb, WkT, bk, (void*)Kb);
    gemm_bf16<1><<<gg, 256, 0, stream>>>(xb, WvT, bv, (void*)VTb);  // V stored transposed
    // 4. causal attention
    attn<<<dim3(SQ / 64, NH), 256, 0, stream>>>(Qb, Kb, VTb, Ctx);
    // 5. output projection (fp32 out, no bias)
    gemm_bf16<2><<<gg, 256, 0, stream>>>(Ctx, WoT, nullptr, d_out);
}

// Round 2
// 565.612 us; speedup vs baseline: 1.3406x; 1.3406x over previous
//
#include <hip/hip_runtime.h>
#include <hip/hip_bf16.h>
#include <stdint.h>

// Problem: B=1, S=4096, HIDDEN=2048, HEADS=16, HEAD_DIM=128, causal MHA.
// All inputs fp32; output fp32. Compute in bf16 MFMA with fp32 accum.
//
// Workspace layout (bytes), total ~112 MB:
//   xb   [4096][2048] bf16 @ 0          (16 MB)
//   WqT  [2048][2048] bf16 @ 16 MB      (8 MB)   (transposed: [out][in])
//   WkT  @ 24 MB, WvT @ 32 MB, WoT @ 40 MB
//   Qb   [4096][2048] bf16 @ 48 MB
//   Kb   [4096][2048] bf16 @ 64 MB
//   VTb  [2048][4096] bf16 @ 80 MB      (V transposed per-head: row h*128+d, col s)
//   Ctx  [4096][2048] bf16 @ 96 MB

#define SQ 4096
#define HID 2048
#define NH 16
#define HD 128

typedef __attribute__((ext_vector_type(8))) short bf16x8;
typedef __attribute__((ext_vector_type(4))) float f32x4;
typedef __attribute__((ext_vector_type(4))) unsigned short us4;

__device__ inline unsigned short f2bf(float f) {
    unsigned int u = __builtin_bit_cast(unsigned int, f);
    u = (u + 0x7FFFu + ((u >> 16) & 1u)) >> 16;
    return (unsigned short)u;
}

__device__ inline void gl2lds16(const void* g, void* l) {
    __builtin_amdgcn_global_load_lds(
        (const __attribute__((address_space(1))) unsigned int*)g,
        (__attribute__((address_space(3))) unsigned int*)l, 16, 0, 0);
}

// ---------------- fp32 -> bf16 convert (grid-stride, float4) ----------------
__global__ void cvt_f32_bf16(const float* __restrict__ src,
                             unsigned short* __restrict__ dst, int n) {
    int i = (blockIdx.x * blockDim.x + threadIdx.x) * 4;
    int stride = gridDim.x * blockDim.x * 4;
    for (; i < n; i += stride) {
        float4 v = *(const float4*)(src + i);
        us4 o;
        o.x = f2bf(v.x); o.y = f2bf(v.y); o.z = f2bf(v.z); o.w = f2bf(v.w);
        *(us4*)(dst + i) = o;
    }
}

// -------- transpose + convert: W [K][N] f32 -> WT [N][K] bf16 (2048x2048) ---
__global__ void transcvt(const float* __restrict__ W, unsigned short* __restrict__ WT) {
    __shared__ float tile[64][65];
    int n0 = blockIdx.x * 64, k0 = blockIdx.y * 64;
    int t = threadIdx.x;
    for (int i = 0; i < 4; i++) {
        int idx = i * 256 + t;          // 0..1023
        int k = idx >> 4;               // 64 rows, 16 float4 per row
        int n4 = (idx & 15) << 2;
        float4 v = *(const float4*)(W + (size_t)(k0 + k) * HID + n0 + n4);
        tile[k][n4 + 0] = v.x; tile[k][n4 + 1] = v.y;
        tile[k][n4 + 2] = v.z; tile[k][n4 + 3] = v.w;
    }
    __syncthreads();
    for (int i = 0; i < 4; i++) {
        int idx = i * 256 + t;
        int n = idx >> 4;
        int k4 = (idx & 15) << 2;
        us4 o;
        o.x = f2bf(tile[k4 + 0][n]); o.y = f2bf(tile[k4 + 1][n]);
        o.z = f2bf(tile[k4 + 2][n]); o.w = f2bf(tile[k4 + 3][n]);
        *(us4*)(WT + (size_t)(n0 + n) * HID + k0 + k4) = o;
    }
}

// ---------------- bf16 GEMM: C[M,N] = A[M,K] @ BT[N,K]^T (+bias) ------------
// M=4096, N=2048, K=2048. 128x128 tile, BK=64, 256 thr = 4 waves (2x2 of 64x64).
// OUTMODE 0: bf16 out [M][N] + bias; 1: bf16 out transposed [N][M] + bias;
//         2: f32 out [M][N], no bias.
template <int OUTMODE>
__global__ __launch_bounds__(256) void gemm_bf16(
    const unsigned short* __restrict__ A, const unsigned short* __restrict__ BT,
    const float* __restrict__ bias, void* __restrict__ C) {
    const int M = 4096, N = 2048, K = 2048;
    __shared__ __align__(16) unsigned short As[128 * 64];
    __shared__ __align__(16) unsigned short Bs[128 * 64];
    int m0 = blockIdx.x * 128, n0 = blockIdx.y * 128;
    int t = threadIdx.x;
    int lane = t & 63, wid = t >> 6;
    int wm = wid >> 1, wn = wid & 1;
    f32x4 acc[4][4] = {};

    for (int k0 = 0; k0 < K; k0 += 64) {
        for (int i = 0; i < 4; i++) {
            int idx = i * 256 + t;           // 1024 x 16B loads per tile
            int r = idx >> 3;                // row 0..127 (8 loads of 8 elems per row)
            int c = (idx & 7) << 3;
            void* ldsA = (void*)(As + ((i * 256 + wid * 64) << 3));
            void* ldsB = (void*)(Bs + ((i * 256 + wid * 64) << 3));
            gl2lds16(A + (size_t)(m0 + r) * K + k0 + c, ldsA);
            gl2lds16(BT + (size_t)(n0 + r) * K + k0 + c, ldsB);
        }
        __syncthreads();
        for (int kk = 0; kk < 2; kk++) {
            int ko = kk * 32 + ((lane >> 4) << 3);
            bf16x8 af[4], bfg[4];
            for (int mf = 0; mf < 4; mf++)
                af[mf] = *(const bf16x8*)(As + (wm * 64 + mf * 16 + (lane & 15)) * 64 + ko);
            for (int nf = 0; nf < 4; nf++)
                bfg[nf] = *(const bf16x8*)(Bs + (wn * 64 + nf * 16 + (lane & 15)) * 64 + ko);
            for (int mf = 0; mf < 4; mf++)
                for (int nf = 0; nf < 4; nf++)
                    acc[mf][nf] = __builtin_amdgcn_mfma_f32_16x16x32_bf16(
                        af[mf], bfg[nf], acc[mf][nf], 0, 0, 0);
        }
        __syncthreads();
    }

    int rbase = (lane >> 4) << 2;
    for (int mf = 0; mf < 4; mf++) {
        for (int nf = 0; nf < 4; nf++) {
            int n_g = n0 + wn * 64 + nf * 16 + (lane & 15);
            int m_base = m0 + wm * 64 + mf * 16 + rbase;
            float b = (OUTMODE == 2) ? 0.f : bias[n_g];
            if (OUTMODE == 0) {
                unsigned short* Cb = (unsigned short*)C;
                for (int r = 0; r < 4; r++)
                    Cb[(size_t)(m_base + r) * N + n_g] = f2bf(acc[mf][nf][r] + b);
            } else if (OUTMODE == 1) {
                unsigned short* Cb = (unsigned short*)C;
                us4 o;
                o.x = f2bf(acc[mf][nf][0] + b); o.y = f2bf(acc[mf][nf][1] + b);
                o.z = f2bf(acc[mf][nf][2] + b); o.w = f2bf(acc[mf][nf][3] + b);
                *(us4*)(Cb + (size_t)n_g * M + m_base) = o;
            } else {
                float* Cf = (float*)C;
                for (int r = 0; r < 4; r++)
                    Cf[(size_t)(m_base + r) * N + n_g] = acc[mf][nf][r];
            }
        }
    }
}

// ---------------- causal flash attention (v2) --------------------------------
// grid (S/64, NH); 256 thr = 4 waves; wave w owns q rows q0+w*16..+15.
// v2: XOR-swizzled LDS (16B-slot granularity, pre-swizzled global source per
// rule "both-sides-or-neither"), double-buffered K/V prefetch, reversed block
// order (longest-work blocks dispatch first).
__global__ __launch_bounds__(256) void attn(
    const unsigned short* __restrict__ Q, const unsigned short* __restrict__ Kc,
    const unsigned short* __restrict__ VT, unsigned short* __restrict__ O) {
    __shared__ __align__(16) unsigned short Kb[2][64 * 128];
    __shared__ __align__(16) unsigned short Vb[2][128 * 64];
    __shared__ __align__(16) unsigned short Pt[4][16 * 64];
    int bx = (int)gridDim.x - 1 - (int)blockIdx.x;   // reversed: big work first
    int q0 = bx * 64;
    int h = blockIdx.y;
    int t = threadIdx.x, lane = t & 63, w = t >> 6;
    int lr = lane & 15, hi = lane >> 4;
    const float scale = 0.08838834764831845f;  // 1/sqrt(128)

    bf16x8 qf[4];
    {
        int qrow = q0 + w * 16 + lr;
        for (int ks = 0; ks < 4; ks++)
            qf[ks] = *(const bf16x8*)(Q + (size_t)qrow * HID + h * HD + ks * 32 + (hi << 3));
    }
    f32x4 o_acc[8] = {};
    float m_r[4], l_r[4];
    for (int r = 0; r < 4; r++) { m_r[r] = -1e30f; l_r[r] = 0.f; }

    // stage K/V tile kv0 into buffer `buf`, swizzled source (linear LDS dest).
    // K logical (r,col): swizzled slot = (col>>3) ^ (r&7). Same for V.
    auto stage = [&](int buf, int kv0) {
        for (int i = 0; i < 4; i++) {
            int idx = i * 256 + t;
            int r = idx >> 4, s = idx & 15;
            gl2lds16(Kc + (size_t)(kv0 + r) * HID + h * HD + ((s ^ (r & 7)) << 3),
                     (void*)(&Kb[buf][(i * 256 + w * 64) << 3]));
            int r2 = idx >> 3, s2 = idx & 7;
            gl2lds16(VT + (size_t)(h * HD + r2) * SQ + kv0 + ((s2 ^ (r2 & 7)) << 3),
                     (void*)(&Vb[buf][(i * 256 + w * 64) << 3]));
        }
    };

    int nt = bx + 1;
    int cur = 0;
    stage(0, 0);
    __syncthreads();

    for (int tile = 0; tile < nt; tile++) {
        int kv0 = tile * 64;
        if (tile + 1 < nt) stage(cur ^ 1, kv0 + 64);   // async prefetch
        const unsigned short* Kl = &Kb[cur][0];
        const unsigned short* Vl = &Vb[cur][0];

        // S = Q K^T  (per wave: 16 q-rows x 64 kv-cols), swizzled K reads
        f32x4 sfr[4];
        for (int c = 0; c < 4; c++) {
            f32x4 s = {0.f, 0.f, 0.f, 0.f};
            for (int ks = 0; ks < 4; ks++) {
                bf16x8 kf = *(const bf16x8*)(Kl + (c * 16 + lr) * 128 +
                                             (((ks * 4 + hi) ^ (lr & 7)) << 3));
                s = __builtin_amdgcn_mfma_f32_16x16x32_bf16(qf[ks], kf, s, 0, 0, 0);
            }
            sfr[c] = s;
        }
        // scale + causal mask
        int rq = q0 + w * 16 + (hi << 2);
        for (int c = 0; c < 4; c++) {
            int kcol = kv0 + c * 16 + lr;
            for (int r = 0; r < 4; r++) {
                float v = sfr[c][r] * scale;
                sfr[c][r] = (kcol <= rq + r) ? v : -1e30f;
            }
        }
        // online softmax: row max across 4 frags + 16-lane group
        float alpha[4];
        for (int r = 0; r < 4; r++) {
            float v = fmaxf(fmaxf(sfr[0][r], sfr[1][r]), fmaxf(sfr[2][r], sfr[3][r]));
            v = fmaxf(v, __shfl_xor(v, 1));
            v = fmaxf(v, __shfl_xor(v, 2));
            v = fmaxf(v, __shfl_xor(v, 4));
            v = fmaxf(v, __shfl_xor(v, 8));
            float mn = fmaxf(m_r[r], v);
            alpha[r] = __expf(m_r[r] - mn);
            m_r[r] = mn;
        }
        float rs[4] = {0.f, 0.f, 0.f, 0.f};
        for (int c = 0; c < 4; c++)
            for (int r = 0; r < 4; r++) {
                float p = __expf(sfr[c][r] - m_r[r]);
                sfr[c][r] = p;
                rs[r] += p;
            }
        for (int r = 0; r < 4; r++) {
            float v = rs[r];
            v += __shfl_xor(v, 1); v += __shfl_xor(v, 2);
            v += __shfl_xor(v, 4); v += __shfl_xor(v, 8);
            l_r[r] = l_r[r] * alpha[r] + v;
        }
        for (int c2 = 0; c2 < 8; c2++)
            for (int r = 0; r < 4; r++) o_acc[c2][r] *= alpha[r];

        // P -> per-wave LDS buffer (swizzled), re-fragment for PV A-operand
        unsigned short* pw = &Pt[w][0];
        for (int c = 0; c < 4; c++)
            for (int r = 0; r < 4; r++) {
                int row = (hi << 2) + r;
                int sslot = c * 2 + (lr >> 3);
                pw[row * 64 + ((sslot ^ (row & 7)) << 3) + (lr & 7)] = f2bf(sfr[c][r]);
            }
        asm volatile("s_waitcnt lgkmcnt(0)" ::: "memory");

        // O += P V   (A = P [16 x 64], B = V [64 x 128] via VT LDS), swizzled
        for (int kk = 0; kk < 2; kk++) {
            bf16x8 pa = *(const bf16x8*)(pw + lr * 64 +
                                         (((kk * 4 + hi) ^ (lr & 7)) << 3));
            for (int c2 = 0; c2 < 8; c2++) {
                bf16x8 bv = *(const bf16x8*)(Vl + (c2 * 16 + lr) * 64 +
                                             (((kk * 4 + hi) ^ (lr & 7)) << 3));
                o_acc[c2] = __builtin_amdgcn_mfma_f32_16x16x32_bf16(pa, bv, o_acc[c2], 0, 0, 0);
            }
        }
        __syncthreads();   // drains prefetch vmcnt + syncs buffer flip
        cur ^= 1;
    }

    for (int c2 = 0; c2 < 8; c2++)
        for (int r = 0; r < 4; r++) {
            int row = q0 + w * 16 + (hi << 2) + r;
            O[(size_t)row * HID + h * HD + c2 * 16 + lr] = f2bf(o_acc[c2][r] / l_r[r]);
        }
}

// ---------------------------------------------------------------------------
extern "C" void kernel_launch(void* const* d_in, const int* in_sizes, int n_in,
                              void* d_out, int out_size, void* d_ws, size_t ws_size,
                              hipStream_t stream) {
    const float* x  = (const float*)d_in[0];
    const float* Wq = (const float*)d_in[1];
    const float* bq = (const float*)d_in[2];
    const float* Wk = (const float*)d_in[3];
    const float* bk = (const float*)d_in[4];
    const float* Wv = (const float*)d_in[5];
    const float* bv = (const float*)d_in[6];
    const float* Wo = (const float*)d_in[7];

    char* ws = (char*)d_ws;
    const size_t MB = 1024 * 1024;
    unsigned short* xb  = (unsigned short*)(ws + 0 * MB);
    unsigned short* WqT = (unsigned short*)(ws + 16 * MB);
    unsigned short* WkT = (unsigned short*)(ws + 24 * MB);
    unsigned short* WvT = (unsigned short*)(ws + 32 * MB);
    unsigned short* WoT = (unsigned short*)(ws + 40 * MB);
    unsigned short* Qb  = (unsigned short*)(ws + 48 * MB);
    unsigned short* Kb  = (unsigned short*)(ws + 64 * MB);
    unsigned short* VTb = (unsigned short*)(ws + 80 * MB);
    unsigned short* Ctx = (unsigned short*)(ws + 96 * MB);

    // 1. x -> bf16
    cvt_f32_bf16<<<8192, 256, 0, stream>>>(x, xb, SQ * HID);
    // 2. weights -> transposed bf16
    dim3 tg(HID / 64, HID / 64);
    transcvt<<<tg, 256, 0, stream>>>(Wq, WqT);
    transcvt<<<tg, 256, 0, stream>>>(Wk, WkT);
    transcvt<<<tg, 256, 0, stream>>>(Wv, WvT);
    transcvt<<<tg, 256, 0, stream>>>(Wo, WoT);
    // 3. QKV projections
    dim3 gg(SQ / 128, HID / 128);
    gemm_bf16<0><<<gg, 256, 0, stream>>>(xb, WqT, bq, (void*)Qb);
    gemm_bf16<0><<<gg, 256, 0, stream>>>(xb, WkT, bk, (void*)Kb);
    gemm_bf16<1><<<gg, 256, 0, stream>>>(xb, WvT, bv, (void*)VTb);  // V stored transposed
    // 4. causal attention
    attn<<<dim3(SQ / 64, NH), 256, 0, stream>>>(Qb, Kb, VTb, Ctx);
    // 5. output projection (fp32 out, no bias)
    gemm_bf16<2><<<gg, 256, 0, stream>>>(Ctx, WoT, nullptr, d_out);
}

// Round 3
// 406.305 us; speedup vs baseline: 1.8662x; 1.3921x over previous
//
#include <hip/hip_runtime.h>
#include <hip/hip_bf16.h>
#include <stdint.h>

// Problem: B=1, S=4096, HIDDEN=2048, HEADS=16, HEAD_DIM=128, causal MHA.
// All inputs fp32; output fp32. Compute in bf16 MFMA with fp32 accum.
//
// Workspace layout (bytes), total ~112 MB:
//   xb   [4096][2048] bf16 @ 0          (16 MB)
//   WqT  [2048][2048] bf16 @ 16 MB      (8 MB)   (transposed: [out][in])
//   WkT  @ 24 MB, WvT @ 32 MB, WoT @ 40 MB
//   Qb   [4096][2048] bf16 @ 48 MB
//   Kb   [4096][2048] bf16 @ 64 MB
//   VTb  [2048][4096] bf16 @ 80 MB      (V transposed per-head: row h*128+d, col s)
//   Ctx  [4096][2048] bf16 @ 96 MB

#define SQ 4096
#define HID 2048
#define NH 16
#define HD 128

typedef __attribute__((ext_vector_type(8))) short bf16x8;
typedef __attribute__((ext_vector_type(4))) float f32x4;
typedef __attribute__((ext_vector_type(4))) unsigned short us4;

__device__ inline unsigned short f2bf(float f) {
    unsigned int u = __builtin_bit_cast(unsigned int, f);
    u = (u + 0x7FFFu + ((u >> 16) & 1u)) >> 16;
    return (unsigned short)u;
}

__device__ inline void gl2lds16(const void* g, void* l) {
    __builtin_amdgcn_global_load_lds(
        (const __attribute__((address_space(1))) unsigned int*)g,
        (__attribute__((address_space(3))) unsigned int*)l, 16, 0, 0);
}

// ---------------- fp32 -> bf16 convert (grid-stride, float4) ----------------
__global__ void cvt_f32_bf16(const float* __restrict__ src,
                             unsigned short* __restrict__ dst, int n) {
    int i = (blockIdx.x * blockDim.x + threadIdx.x) * 4;
    int stride = gridDim.x * blockDim.x * 4;
    for (; i < n; i += stride) {
        float4 v = *(const float4*)(src + i);
        us4 o;
        o.x = f2bf(v.x); o.y = f2bf(v.y); o.z = f2bf(v.z); o.w = f2bf(v.w);
        *(us4*)(dst + i) = o;
    }
}

// -------- transpose + convert: W [K][N] f32 -> WT [N][K] bf16 (2048x2048) ---
__global__ void transcvt(const float* __restrict__ W, unsigned short* __restrict__ WT) {
    __shared__ float tile[64][65];
    int n0 = blockIdx.x * 64, k0 = blockIdx.y * 64;
    int t = threadIdx.x;
    for (int i = 0; i < 4; i++) {
        int idx = i * 256 + t;          // 0..1023
        int k = idx >> 4;               // 64 rows, 16 float4 per row
        int n4 = (idx & 15) << 2;
        float4 v = *(const float4*)(W + (size_t)(k0 + k) * HID + n0 + n4);
        tile[k][n4 + 0] = v.x; tile[k][n4 + 1] = v.y;
        tile[k][n4 + 2] = v.z; tile[k][n4 + 3] = v.w;
    }
    __syncthreads();
    for (int i = 0; i < 4; i++) {
        int idx = i * 256 + t;
        int n = idx >> 4;
        int k4 = (idx & 15) << 2;
        us4 o;
        o.x = f2bf(tile[k4 + 0][n]); o.y = f2bf(tile[k4 + 1][n]);
        o.z = f2bf(tile[k4 + 2][n]); o.w = f2bf(tile[k4 + 3][n]);
        *(us4*)(WT + (size_t)(n0 + n) * HID + k0 + k4) = o;
    }
}

// ---------------- bf16 GEMM: C[M,N] = A[M,K] @ BT[N,K]^T (+bias) ------------
// M=4096, N=2048, K=2048. 128x128 tile, BK=64, 256 thr = 4 waves (2x2 of 64x64).
// OUTMODE 0: bf16 out [M][N] + bias; 1: bf16 out transposed [N][M] + bias;
//         2: f32 out [M][N], no bias.
template <int OUTMODE>
__global__ __launch_bounds__(256) void gemm_bf16(
    const unsigned short* __restrict__ A, const unsigned short* __restrict__ BT,
    const float* __restrict__ bias, void* __restrict__ C) {
    const int M = 4096, N = 2048, K = 2048;
    __shared__ __align__(16) unsigned short As[128 * 64];
    __shared__ __align__(16) unsigned short Bs[128 * 64];
    int m0 = blockIdx.x * 128, n0 = blockIdx.y * 128;
    int t = threadIdx.x;
    int lane = t & 63, wid = t >> 6;
    int wm = wid >> 1, wn = wid & 1;
    f32x4 acc[4][4] = {};

    for (int k0 = 0; k0 < K; k0 += 64) {
        for (int i = 0; i < 4; i++) {
            int idx = i * 256 + t;           // 1024 x 16B loads per tile
            int r = idx >> 3;                // row 0..127 (8 loads of 8 elems per row)
            int c = (idx & 7) << 3;
            void* ldsA = (void*)(As + ((i * 256 + wid * 64) << 3));
            void* ldsB = (void*)(Bs + ((i * 256 + wid * 64) << 3));
            gl2lds16(A + (size_t)(m0 + r) * K + k0 + c, ldsA);
            gl2lds16(BT + (size_t)(n0 + r) * K + k0 + c, ldsB);
        }
        __syncthreads();
        for (int kk = 0; kk < 2; kk++) {
            int ko = kk * 32 + ((lane >> 4) << 3);
            bf16x8 af[4], bfg[4];
            for (int mf = 0; mf < 4; mf++)
                af[mf] = *(const bf16x8*)(As + (wm * 64 + mf * 16 + (lane & 15)) * 64 + ko);
            for (int nf = 0; nf < 4; nf++)
                bfg[nf] = *(const bf16x8*)(Bs + (wn * 64 + nf * 16 + (lane & 15)) * 64 + ko);
            for (int mf = 0; mf < 4; mf++)
                for (int nf = 0; nf < 4; nf++)
                    acc[mf][nf] = __builtin_amdgcn_mfma_f32_16x16x32_bf16(
                        af[mf], bfg[nf], acc[mf][nf], 0, 0, 0);
        }
        __syncthreads();
    }

    int rbase = (lane >> 4) << 2;
    for (int mf = 0; mf < 4; mf++) {
        for (int nf = 0; nf < 4; nf++) {
            int n_g = n0 + wn * 64 + nf * 16 + (lane & 15);
            int m_base = m0 + wm * 64 + mf * 16 + rbase;
            float b = (OUTMODE == 2) ? 0.f : bias[n_g];
            if (OUTMODE == 0) {
                unsigned short* Cb = (unsigned short*)C;
                for (int r = 0; r < 4; r++)
                    Cb[(size_t)(m_base + r) * N + n_g] = f2bf(acc[mf][nf][r] + b);
            } else if (OUTMODE == 1) {
                unsigned short* Cb = (unsigned short*)C;
                us4 o;
                o.x = f2bf(acc[mf][nf][0] + b); o.y = f2bf(acc[mf][nf][1] + b);
                o.z = f2bf(acc[mf][nf][2] + b); o.w = f2bf(acc[mf][nf][3] + b);
                *(us4*)(Cb + (size_t)n_g * M + m_base) = o;
            } else {
                float* Cf = (float*)C;
                for (int r = 0; r < 4; r++)
                    Cf[(size_t)(m_base + r) * N + n_g] = acc[mf][nf][r];
            }
        }
    }
}

// ---------------- causal flash attention (v3) --------------------------------
// grid (16, NH); 512 thr = 8 waves. Block bx processes q-strip bx then strip
// 31-bx (128 q-rows each) -> every block does exactly 68 KV-tiles: perfect
// balance, 256 blocks = 1/CU, all resident. Wave w owns q rows qbase+w*16..+15.
// K/V double-buffered + prefetch; XOR-swizzled LDS (pre-swizzled global src).
__global__ __launch_bounds__(512) void attn(
    const unsigned short* __restrict__ Q, const unsigned short* __restrict__ Kc,
    const unsigned short* __restrict__ VT, unsigned short* __restrict__ O) {
    __shared__ __align__(16) unsigned short Kb[2][64 * 128];
    __shared__ __align__(16) unsigned short Vb[2][128 * 64];
    __shared__ __align__(16) unsigned short Pt[8][16 * 64];
    int bx = blockIdx.x;
    int h = blockIdx.y;
    int t = threadIdx.x, lane = t & 63, w = t >> 6;
    int lr = lane & 15, hi = lane >> 4;
    const float scale = 0.08838834764831845f;  // 1/sqrt(128)

    // stage K/V tile kv0 into buffer `buf`, swizzled source (linear LDS dest).
    auto stage = [&](int buf, int kv0) {
        for (int i = 0; i < 2; i++) {
            int idx = i * 512 + t;            // 0..1023
            int r = idx >> 4, s = idx & 15;   // K: 64 rows x 16 slots
            gl2lds16(Kc + (size_t)(kv0 + r) * HID + h * HD + ((s ^ (r & 7)) << 3),
                     (void*)(&Kb[buf][(i * 512 + w * 64) << 3]));
            int r2 = idx >> 3, s2 = idx & 7;  // VT: 128 rows x 8 slots
            gl2lds16(VT + (size_t)(h * HD + r2) * SQ + kv0 + ((s2 ^ (r2 & 7)) << 3),
                     (void*)(&Vb[buf][(i * 512 + w * 64) << 3]));
        }
    };

    int strips[2] = {bx, 31 - bx};
    for (int sp = 0; sp < 2; sp++) {
        int qbase = strips[sp] * 128;
        int wq0 = qbase + w * 16;

        stage(0, 0);
        bf16x8 qf[4];
        {
            int qrow = wq0 + lr;
            for (int ks = 0; ks < 4; ks++)
                qf[ks] = *(const bf16x8*)(Q + (size_t)qrow * HID + h * HD + ks * 32 + (hi << 3));
        }
        f32x4 o_acc[8] = {};
        float m_r[4], l_r[4];
        for (int r = 0; r < 4; r++) { m_r[r] = -1e30f; l_r[r] = 0.f; }
        __syncthreads();

        int nt = (qbase >> 6) + 2;   // 2*strip + 2
        int cur = 0;
        for (int tile = 0; tile < nt; tile++) {
            int kv0 = tile * 64;
            if (tile + 1 < nt) stage(cur ^ 1, kv0 + 64);   // async prefetch
            const unsigned short* Kl = &Kb[cur][0];
            const unsigned short* Vl = &Vb[cur][0];

            if (kv0 <= wq0 + 15) {   // not fully above this wave's diagonal
                // S = Q K^T  (16 q-rows x 64 kv-cols), swizzled K reads
                f32x4 sfr[4];
                for (int c = 0; c < 4; c++) {
                    f32x4 s = {0.f, 0.f, 0.f, 0.f};
                    for (int ks = 0; ks < 4; ks++) {
                        bf16x8 kf = *(const bf16x8*)(Kl + (c * 16 + lr) * 128 +
                                                     (((ks * 4 + hi) ^ (lr & 7)) << 3));
                        s = __builtin_amdgcn_mfma_f32_16x16x32_bf16(qf[ks], kf, s, 0, 0, 0);
                    }
                    sfr[c] = s;
                }
                // scale + causal mask (only tiles straddling the diagonal)
                int rq = wq0 + (hi << 2);
                if (kv0 + 63 > wq0) {
                    for (int c = 0; c < 4; c++) {
                        int kcol = kv0 + c * 16 + lr;
                        for (int r = 0; r < 4; r++) {
                            float v = sfr[c][r] * scale;
                            sfr[c][r] = (kcol <= rq + r) ? v : -1e30f;
                        }
                    }
                } else {
                    for (int c = 0; c < 4; c++)
                        for (int r = 0; r < 4; r++) sfr[c][r] *= scale;
                }
                // online softmax
                float alpha[4];
                for (int r = 0; r < 4; r++) {
                    float v = fmaxf(fmaxf(sfr[0][r], sfr[1][r]), fmaxf(sfr[2][r], sfr[3][r]));
                    v = fmaxf(v, __shfl_xor(v, 1));
                    v = fmaxf(v, __shfl_xor(v, 2));
                    v = fmaxf(v, __shfl_xor(v, 4));
                    v = fmaxf(v, __shfl_xor(v, 8));
                    float mn = fmaxf(m_r[r], v);
                    alpha[r] = __expf(m_r[r] - mn);
                    m_r[r] = mn;
                }
                float rs[4] = {0.f, 0.f, 0.f, 0.f};
                for (int c = 0; c < 4; c++)
                    for (int r = 0; r < 4; r++) {
                        float p = __expf(sfr[c][r] - m_r[r]);
                        sfr[c][r] = p;
                        rs[r] += p;
                    }
                for (int r = 0; r < 4; r++) {
                    float v = rs[r];
                    v += __shfl_xor(v, 1); v += __shfl_xor(v, 2);
                    v += __shfl_xor(v, 4); v += __shfl_xor(v, 8);
                    l_r[r] = l_r[r] * alpha[r] + v;
                }
                for (int c2 = 0; c2 < 8; c2++)
                    for (int r = 0; r < 4; r++) o_acc[c2][r] *= alpha[r];

                // P -> per-wave LDS buffer (swizzled), re-fragment for PV A-op
                unsigned short* pw = &Pt[w][0];
                for (int c = 0; c < 4; c++)
                    for (int r = 0; r < 4; r++) {
                        int row = (hi << 2) + r;
                        int sslot = c * 2 + (lr >> 3);
                        pw[row * 64 + ((sslot ^ (row & 7)) << 3) + (lr & 7)] = f2bf(sfr[c][r]);
                    }
                asm volatile("s_waitcnt lgkmcnt(0)" ::: "memory");

                // O += P V (A = P [16x64], B = V via VT LDS), swizzled
                for (int kk = 0; kk < 2; kk++) {
                    bf16x8 pa = *(const bf16x8*)(pw + lr * 64 +
                                                 (((kk * 4 + hi) ^ (lr & 7)) << 3));
                    for (int c2 = 0; c2 < 8; c2++) {
                        bf16x8 bv = *(const bf16x8*)(Vl + (c2 * 16 + lr) * 64 +
                                                     (((kk * 4 + hi) ^ (lr & 7)) << 3));
                        o_acc[c2] = __builtin_amdgcn_mfma_f32_16x16x32_bf16(pa, bv, o_acc[c2], 0, 0, 0);
                    }
                }
            }
            __syncthreads();   // drains prefetch vmcnt + syncs buffer flip
            cur ^= 1;
        }

        for (int c2 = 0; c2 < 8; c2++)
            for (int r = 0; r < 4; r++) {
                int row = wq0 + (hi << 2) + r;
                O[(size_t)row * HID + h * HD + c2 * 16 + lr] = f2bf(o_acc[c2][r] / l_r[r]);
            }
    }
}

// ---------------------------------------------------------------------------
extern "C" void kernel_launch(void* const* d_in, const int* in_sizes, int n_in,
                              void* d_out, int out_size, void* d_ws, size_t ws_size,
                              hipStream_t stream) {
    const float* x  = (const float*)d_in[0];
    const float* Wq = (const float*)d_in[1];
    const float* bq = (const float*)d_in[2];
    const float* Wk = (const float*)d_in[3];
    const float* bk = (const float*)d_in[4];
    const float* Wv = (const float*)d_in[5];
    const float* bv = (const float*)d_in[6];
    const float* Wo = (const float*)d_in[7];

    char* ws = (char*)d_ws;
    const size_t MB = 1024 * 1024;
    unsigned short* xb  = (unsigned short*)(ws + 0 * MB);
    unsigned short* WqT = (unsigned short*)(ws + 16 * MB);
    unsigned short* WkT = (unsigned short*)(ws + 24 * MB);
    unsigned short* WvT = (unsigned short*)(ws + 32 * MB);
    unsigned short* WoT = (unsigned short*)(ws + 40 * MB);
    unsigned short* Qb  = (unsigned short*)(ws + 48 * MB);
    unsigned short* Kbuf= (unsigned short*)(ws + 64 * MB);
    unsigned short* VTb = (unsigned short*)(ws + 80 * MB);
    unsigned short* Ctx = (unsigned short*)(ws + 96 * MB);

    // 1. x -> bf16
    cvt_f32_bf16<<<8192, 256, 0, stream>>>(x, xb, SQ * HID);
    // 2. weights -> transposed bf16
    dim3 tg(HID / 64, HID / 64);
    transcvt<<<tg, 256, 0, stream>>>(Wq, WqT);
    transcvt<<<tg, 256, 0, stream>>>(Wk, WkT);
    transcvt<<<tg, 256, 0, stream>>>(Wv, WvT);
    transcvt<<<tg, 256, 0, stream>>>(Wo, WoT);
    // 3. QKV projections
    dim3 gg(SQ / 128, HID / 128);
    gemm_bf16<0><<<gg, 256, 0, stream>>>(xb, WqT, bq, (void*)Qb);
    gemm_bf16<0><<<gg, 256, 0, stream>>>(xb, WkT, bk, (void*)Kbuf);
    gemm_bf16<1><<<gg, 256, 0, stream>>>(xb, WvT, bv, (void*)VTb);  // V stored transposed
    // 4. causal attention
    attn<<<dim3(16, NH), 512, 0, stream>>>(Qb, Kbuf, VTb, Ctx);
    // 5. output projection (fp32 out, no bias)
    gemm_bf16<2><<<gg, 256, 0, stream>>>(Ctx, WoT, nullptr, d_out);
}